// Round 4
// baseline (14271.094 us; speedup 1.0000x reference)
//
#include <hip/hip_runtime.h>

#define HH 64
#define TT 12
#define TOUT 12
#define CC 10
#define BNTOT 131072

// sigmoid / tanh via exp + rcp (saturate correctly at +-inf through rcp)
__device__ __forceinline__ float sigm(float x){
  return __builtin_amdgcn_rcpf(1.0f + __expf(-x));
}
__device__ __forceinline__ float tanh_f(float x){
  return 1.0f - 2.0f * __builtin_amdgcn_rcpf(1.0f + __expf(2.0f * x));
}

// One GRU step. h[] lives in registers (static indexing only); the LDS column
// hn_col (stride 256 floats per row) mirrors h so the dynamic-j write of
// h_new[j] and dynamic-j read of old h[j] never touch scratch.
// Thread t's column {t, 256+t, ...} is disjoint from all others -> no barrier.
template<int F>
__device__ __forceinline__ void gru_step(
    float h[HH], float x0, float x1,
    const float* __restrict__ whh, const float* __restrict__ wih,
    const float* __restrict__ bih, const float* __restrict__ bhh,
    float* hn_col)
{
  #pragma unroll 1
  for (int j = 0; j < HH; ++j){
    float ar = bhh[j], az = bhh[HH + j], an = bhh[2*HH + j];
    const float* wr = whh + j*HH;
    const float* wz = whh + (HH + j)*HH;
    const float* wn = whh + (2*HH + j)*HH;
    float hjold = hn_col[j * 256];          // old h[j] (LDS mirrors h)
    #pragma unroll
    for (int k = 0; k < HH; ++k){
      float hk = h[k];
      ar = fmaf(hk, wr[k], ar);
      az = fmaf(hk, wz[k], az);
      an = fmaf(hk, wn[k], an);
    }
    float gr, gz, gn;
    if (F == 2){
      gr = fmaf(x0, wih[(j)*2],        fmaf(x1, wih[(j)*2 + 1],        bih[j]));
      gz = fmaf(x0, wih[(HH+j)*2],     fmaf(x1, wih[(HH+j)*2 + 1],     bih[HH + j]));
      gn = fmaf(x0, wih[(2*HH+j)*2],   fmaf(x1, wih[(2*HH+j)*2 + 1],   bih[2*HH + j]));
    } else {
      gr = fmaf(x0, wih[j],        bih[j]);
      gz = fmaf(x0, wih[HH + j],   bih[HH + j]);
      gn = fmaf(x0, wih[2*HH + j], bih[2*HH + j]);
    }
    float r = sigm(gr + ar);
    float z = sigm(gz + az);
    float n = tanh_f(fmaf(r, an, gn));
    hn_col[j * 256] = (1.0f - z) * n + z * hjold;
  }
  #pragma unroll
  for (int k = 0; k < HH; ++k) h[k] = hn_col[k * 256];
}

struct W {
  const float* ewih; const float* ewhh; const float* ebih; const float* ebhh;
  const float* dwih; const float* dwhh; const float* dbih; const float* dbhh;
  const float* l1w;  const float* l1b;  const float* l2w;  const float* l2b;
  const float* emb;
};

__global__ __launch_bounds__(256, 2) void rnn_main(
    const float* __restrict__ X, W wp, float* __restrict__ out)
{
  __shared__ float hn_lds[HH * 256];        // 64 KB: per-thread h mirror column
  const int tid = threadIdx.x;
  const int bn = blockIdx.x * 256 + tid;
  float* hn_col = hn_lds + tid;             // lane-stride 1 -> 2-way bank alias (free)

  // Load this sample's Xr[t][f]
  float Xr0[TT], Xr1[TT];
  {
    const float* xp = X + (size_t)bn * (TT * 2);
    #pragma unroll
    for (int t = 0; t < TT; ++t){ Xr0[t] = xp[2*t]; Xr1[t] = xp[2*t + 1]; }
  }

  // w0[o] = sum_t query[t] * embed1[t][o]
  float w0[TOUT];
  #pragma unroll
  for (int o = 0; o < TOUT; ++o){
    float a = 0.f;
    #pragma unroll
    for (int t = 0; t < TT; ++t) a = fmaf(Xr0[t], wp.emb[t * TOUT + o], a);
    w0[o] = a;
  }

  // online softmax state over configs c
  float m = -1e30f, dsum = 0.f;
  float num[TOUT];
  #pragma unroll
  for (int o = 0; o < TOUT; ++o) num[o] = 0.f;

  float h[HH];
  #pragma unroll 1
  for (int c = 0; c < CC; ++c){
    const float* ewhh = wp.ewhh + c * 192 * HH;
    const float* ewih = wp.ewih + c * 192 * 2;
    const float* ebih = wp.ebih + c * 192;
    const float* ebhh = wp.ebhh + c * 192;
    const float* dwhh = wp.dwhh + c * 192 * HH;
    const float* dwih = wp.dwih + c * 192;
    const float* dbih = wp.dbih + c * 192;
    const float* dbhh = wp.dbhh + c * 192;
    const float* w2   = wp.l2w + c * 144;
    const float* b2   = wp.l2b + c * TOUT;
    const float* l1w  = wp.l1w + c * HH;
    const float l1b   = wp.l1b[c];

    #pragma unroll
    for (int k = 0; k < HH; ++k){ h[k] = 0.f; hn_col[k * 256] = 0.f; }

    // encoder: s = 3+c steps, input hv[j] = (sum_t Xr[t,:] * w2[j,t]) + b2[j]
    const int s = 3 + c;
    #pragma unroll 1
    for (int j = 0; j < s; ++j){
      float b = b2[j];
      float hv0 = b, hv1 = b;
      #pragma unroll
      for (int t = 0; t < TT; ++t){
        float w = w2[j * TT + t];
        hv0 = fmaf(Xr0[t], w, hv0);
        hv1 = fmaf(Xr1[t], w, hv1);
      }
      gru_step<2>(h, hv0, hv1, ewhh, ewih, ebih, ebhh, hn_col);
    }

    // decoder: 12 steps, scalar input feedback. Fully unrolled so va[] has
    // static indices (stays in VGPRs — no scratch).
    float va[TOUT];
    float lv = Xr0[TT - 1];
    #pragma unroll
    for (int t = 0; t < TOUT; ++t){
      gru_step<1>(h, lv, 0.f, dwhh, dwih, dbih, dbhh, hn_col);
      float v = l1b;
      #pragma unroll
      for (int k = 0; k < HH; ++k) v = fmaf(h[k], l1w[k], v);
      va[t] = v;
      lv = v;
    }

    // online softmax update with this config's 12 decoder outputs
    float l = 0.f;
    #pragma unroll
    for (int o = 0; o < TOUT; ++o) l = fmaf(w0[o], va[o], l);
    float nm = fmaxf(m, l);
    float aa = __expf(m - nm);
    float ee = __expf(l - nm);
    dsum = dsum * aa + ee;
    #pragma unroll
    for (int o = 0; o < TOUT; ++o) num[o] = num[o] * aa + va[o] * ee;
    m = nm;
  }

  float inv = 1.0f / dsum;
  #pragma unroll
  for (int o = 0; o < TOUT; ++o) out[(size_t)bn * TOUT + o] = num[o] * inv;
}

extern "C" void kernel_launch(void* const* d_in, const int* in_sizes, int n_in,
                              void* d_out, int out_size, void* d_ws, size_t ws_size,
                              hipStream_t stream) {
  // Expected dict order: 0=A 1=X 2=enc_w_ih 3=enc_w_hh 4=enc_b_ih 5=enc_b_hh
  //   6=dec_w_ih 7=dec_w_hh 8=dec_b_ih 9=dec_b_hh 10=lin1_w 11=lin1_b
  //   12=lin2_w 13=lin2_b 14=embed1
  // Inputs proven fp32-stored (bf16 reinterpretation NaNs; fp32 path doesn't).
  // OUTPUT: fp32 per the contract ("reference's OUTPUT dtype ... else float*")
  // — reference returns jnp.float32. Round 2/3's 0.455 absmax is consistent
  // with correct values written in the WRONG format (bf16 ushorts into an
  // fp32 buffer: top-half decode + zero tail -> ~0.45).
  //
  // Insurance: resolve input indices by size fingerprint instead of fixed
  // positions (robust to the unused A being pruned / list shifts).
  int iX = 1, iW = 2;  // defaults: dict order with A at 0
  for (int i = 0; i < n_in; ++i){
    if (in_sizes[i] == 3145728) iX = i;          // X = 256*512*12*2 (unique)
    if (in_sizes[i] == 3840)   { iW = i; break; } // enc_w_ih = 10*192*2 (unique, first)
  }

  W wp;
  wp.ewih = (const float*)d_in[iW + 0];
  wp.ewhh = (const float*)d_in[iW + 1];
  wp.ebih = (const float*)d_in[iW + 2];
  wp.ebhh = (const float*)d_in[iW + 3];
  wp.dwih = (const float*)d_in[iW + 4];
  wp.dwhh = (const float*)d_in[iW + 5];
  wp.dbih = (const float*)d_in[iW + 6];
  wp.dbhh = (const float*)d_in[iW + 7];
  wp.l1w  = (const float*)d_in[iW + 8];
  wp.l1b  = (const float*)d_in[iW + 9];
  wp.l2w  = (const float*)d_in[iW + 10];
  wp.l2b  = (const float*)d_in[iW + 11];
  wp.emb  = (const float*)d_in[iW + 12];

  rnn_main<<<BNTOT / 256, 256, 0, stream>>>(
      (const float*)d_in[iX], wp, (float*)d_out);
}